// Round 9
// baseline (297.830 us; speedup 1.0000x reference)
//
#include <hip/hip_runtime.h>

#define HH_EPS 1e-8f

constexpr int D     = 2048;            // feature dim
constexpr int K     = 16;              // number of reflections
constexpr int RR    = 2;               // rows per wave (h = 64 VGPRs)
constexpr int CH    = D / (64 * 4);    // 8 float4 chunks per lane per row
constexpr int NROWS = 4 * 4096;        // B * S = 16384
constexpr int WPB   = 4;               // waves per block (256 threads)
constexpr int SPAD  = 17;              // 16 partials + 1 pad

// ---------------------------------------------------------------------------
// Kernel 1: Gram matrix G[i][j] = v_i . v_j  (one wave per (i,j) pair).
// ---------------------------------------------------------------------------
__global__ void __launch_bounds__(64) hh_gram_kernel(const float* __restrict__ vecs,
                                                     float* __restrict__ G) {
    int i = blockIdx.x >> 4, j = blockIdx.x & 15;
    int lane = threadIdx.x;
    const float4* a = (const float4*)(vecs + i * D);
    const float4* b = (const float4*)(vecs + j * D);
    float s = 0.f;
#pragma unroll
    for (int c = 0; c < CH; ++c) {
        float4 x = a[c * 64 + lane], y = b[c * 64 + lane];
        s += x.x * y.x + x.y * y.y + x.z * y.z + x.w * y.w;
    }
#pragma unroll
    for (int off = 32; off >= 1; off >>= 1) s += __shfl_xor(s, off);
    if (lane == 0) G[i * K + j] = s;
}

// ---------------------------------------------------------------------------
// Kernel 2: build T (upper triangular): H0..H15 = I - V T V^T (larft).
//   T[k][k] = beta_k = 2 / max(G[k][k], EPS)
//   T[i][k] = -beta_k * sum_{j=i}^{k-1} T[i][j] * G[j][k]   (i < k)
// Lower triangle stays 0 (apply kernel sums over all k).
// ---------------------------------------------------------------------------
__global__ void __launch_bounds__(256) hh_buildT_kernel(const float* __restrict__ G,
                                                        float* __restrict__ T) {
    __shared__ float sG[K * K], sT[K * K];
    int t = threadIdx.x;
    sG[t] = G[t]; sT[t] = 0.f;
    __syncthreads();
    for (int k = 0; k < K; ++k) {
        float beta = 2.f / fmaxf(sG[k * K + k], HH_EPS);
        if (t == k) sT[k * K + k] = beta;
        else if (t < k) {
            float s = 0.f;
            for (int j = t; j < k; ++j) s += sT[t * K + j] * sG[j * K + k];
            sT[t * K + k] = -beta * s;
        }
        __syncthreads();
    }
    T[t] = sT[t];
}

// ---------------------------------------------------------------------------
// Dot phase k: per-j, consume va[j] then reload it IN PLACE with v_{knext}.
// The reload issues as soon as va[j]'s last FMA has read it (register
// rename), giving ~a full phase of load-latency cover with ZERO extra
// registers — this replaces the va/vb double-buffer. Partials fold 64->16
// lanes via 2 butterfly steps; lanes 0-15 write per-wave LDS.
// ---------------------------------------------------------------------------
__device__ __forceinline__ void wy_dot_phase(const float4 (&h)[RR][CH],
                                             float4 (&va)[CH],
                                             const float4* __restrict__ v4,
                                             int knext, int lane,
                                             float* __restrict__ myP, int k) {
    float a0x = 0.f, a0y = 0.f, a0z = 0.f, a0w = 0.f;
    float a1x = 0.f, a1y = 0.f, a1z = 0.f, a1w = 0.f;
#pragma unroll
    for (int j = 0; j < CH; ++j) {
        float4 v = va[j];
        a0x += h[0][j].x * v.x; a0y += h[0][j].y * v.y;
        a0z += h[0][j].z * v.z; a0w += h[0][j].w * v.w;
        a1x += h[1][j].x * v.x; a1y += h[1][j].y * v.y;
        a1z += h[1][j].z * v.z; a1w += h[1][j].w * v.w;
        va[j] = v4[knext * (D / 4) + j * 64 + lane];   // reload for next phase
    }
    float s0 = (a0x + a0y) + (a0z + a0w);
    float s1 = (a1x + a1y) + (a1z + a1w);
    s0 += __shfl_xor(s0, 32); s0 += __shfl_xor(s0, 16);
    s1 += __shfl_xor(s1, 32); s1 += __shfl_xor(s1, 16);
    if (lane < 16) {
        myP[(0 * K + k) * SPAD + lane] = s0;
        myP[(1 * K + k) * SPAD + lane] = s1;
    }
}

// ---------------------------------------------------------------------------
// Update phase k: h[r] -= w_r[k] * v_k, same consume-then-reload pattern.
// ---------------------------------------------------------------------------
__device__ __forceinline__ void wy_upd_phase(float4 (&h)[RR][CH],
                                             float4 (&va)[CH],
                                             const float4* __restrict__ v4,
                                             int knext, int lane,
                                             float w0, float w1) {
#pragma unroll
    for (int j = 0; j < CH; ++j) {
        float4 v = va[j];
        h[0][j].x -= w0 * v.x; h[0][j].y -= w0 * v.y;
        h[0][j].z -= w0 * v.z; h[0][j].w -= w0 * v.w;
        h[1][j].x -= w1 * v.x; h[1][j].y -= w1 * v.y;
        h[1][j].z -= w1 * v.z; h[1][j].w -= w1 * v.w;
        va[j] = v4[knext * (D / 4) + j * 64 + lane];
    }
}

// ---------------------------------------------------------------------------
// Apply kernel: compact-WY, no-spill R7/R8 structure with the per-wave
// register footprint halved to break the 2-waves/SIMD register ceiling:
// R8 showed LDS was not the occupancy limiter — h[4][8]+va/vb ~256 unified
// regs was (waves/SIMD halve at 64/128/256). RR=2 + in-place va reload
// puts demand at ~116 regs; launch_bounds(256,4) pins the 128 cap ->
// 4 waves/SIMD. Everything else unchanged (LDS partials, runtime k-loops).
// ---------------------------------------------------------------------------
__global__ void __launch_bounds__(256, 4)
hh_apply_wy(const float* __restrict__ h_in, const float* __restrict__ vecs,
            const float* __restrict__ Tmat, float* __restrict__ h_out) {
    __shared__ float sP[WPB * RR * K * SPAD];   // 8.7 KB: per-wave partials
    __shared__ float sD[WPB * RR * K];          // 0.5 KB: reduced dots
    __shared__ float sW[WPB * RR * K];          // 0.5 KB: w = P.T
    __shared__ float sT[K * K];                 // 1 KB

    const int t    = threadIdx.x;
    const int wv   = t >> 6;
    const int lane = t & 63;
    const int gw   = blockIdx.x * WPB + wv;
    const size_t rbase = (size_t)gw * RR;

    // h rows into registers (issued first; latency hides under v0 + sT).
    float4 h[RR][CH];
    const float4* hin4 = (const float4*)h_in;
#pragma unroll
    for (int r = 0; r < RR; ++r)
#pragma unroll
        for (int j = 0; j < CH; ++j)
            h[r][j] = hin4[(rbase + r) * (D / 4) + j * 64 + lane];

    const float4* v4 = (const float4*)vecs;
    float4 va[CH];
#pragma unroll
    for (int j = 0; j < CH; ++j) va[j] = v4[j * 64 + lane];   // v_0

    sT[t] = Tmat[t];
    __syncthreads();   // sT is block-shared; only barrier in the kernel

    float* myP = sP + wv * (RR * K * SPAD);
    float* myD = sD + wv * (RR * K);
    float* myW = sW + wv * (RR * K);

    // ---- dot pass: phase k consumes v_k, reloads v_{k+1} (k=15 wraps to
    // v_0, leaving va ready for the update pass) -------------------------
#pragma unroll 1
    for (int k = 0; k < K; ++k)
        wy_dot_phase(h, va, v4, (k + 1) & 15, lane, myP, k);

    // ---- final reduce: lane l -> k=l&15, segment l>>4 reads 4 of 16 ----
    const int kk  = lane & 15;
    const int seg = lane >> 4;
#pragma unroll
    for (int r = 0; r < RR; ++r) {
        float s = 0.f;
#pragma unroll
        for (int i = 0; i < 4; ++i)
            s += myP[(r * K + kk) * SPAD + seg * 4 + i];
        s += __shfl_xor(s, 16);
        s += __shfl_xor(s, 32);
        if (lane < 16) myD[r * K + kk] = s;
    }

    // ---- w[j] = sum_k P[k] * T[k][j] (lower triangle of T is 0) --------
#pragma unroll
    for (int r = 0; r < RR; ++r) {
        float wsum = 0.f;
#pragma unroll
        for (int k2 = 0; k2 < K; ++k2)
            wsum += myD[r * K + k2] * sT[k2 * K + kk];   // myD uniform-bcast
        if (lane < 16) myW[r * K + kk] = wsum;
    }

    // ---- update pass: h -= sum_k w_k v_k, same reload rotation ---------
#pragma unroll 1
    for (int k = 0; k < K; ++k) {
        float w0 = myW[0 * K + k];   // uniform address -> LDS broadcast
        float w1 = myW[1 * K + k];
        wy_upd_phase(h, va, v4, (k + 1) & 15, lane, w0, w1);
    }

    // ---- store (h untouched in global between load and here) -----------
#pragma unroll
    for (int r = 0; r < RR; ++r) {
        float4* row = (float4*)h_out + (rbase + r) * (D / 4);
#pragma unroll
        for (int j = 0; j < CH; ++j)
            row[j * 64 + lane] = h[r][j];
    }
}

extern "C" void kernel_launch(void* const* d_in, const int* in_sizes, int n_in,
                              void* d_out, int out_size, void* d_ws, size_t ws_size,
                              hipStream_t stream) {
    const float* h    = (const float*)d_in[0];   // [4,4096,2048] fp32
    const float* vecs = (const float*)d_in[1];   // [16,2048] fp32
    float* out        = (float*)d_out;           // [4,4096,2048] fp32

    float* G  = (float*)d_ws;                    // 256 floats
    float* Tm = G + K * K;                       // 256 floats

    hh_gram_kernel<<<K * K, 64, 0, stream>>>(vecs, G);
    hh_buildT_kernel<<<1, 256, 0, stream>>>(G, Tm);

    int blocks = NROWS / (RR * WPB);             // 2048 blocks of 4 waves
    hh_apply_wy<<<blocks, 256, 0, stream>>>(h, vecs, Tm, out);
}

// Round 10
// 261.833 us; speedup vs baseline: 1.1375x; 1.1375x over previous
//
#include <hip/hip_runtime.h>

#define HH_EPS 1e-8f

constexpr int D     = 2048;            // feature dim
constexpr int K     = 16;              // number of reflections
constexpr int RR    = 2;               // rows per wave (h = 64 VGPRs)
constexpr int CH    = D / (64 * 4);    // 8 float4 chunks per lane per row
constexpr int NROWS = 4 * 4096;        // B * S = 16384
constexpr int TPB   = 1024;            // 16 waves/block, 1 block/CU (LDS-bound)
constexpr int WPB   = TPB / 64;        // 16 waves
constexpr int SPAD  = 9;               // 8 folded partials + 1 pad

// ---------------------------------------------------------------------------
// Kernel 1: Gram matrix G[i][j] = v_i . v_j  (one wave per (i,j) pair).
// ---------------------------------------------------------------------------
__global__ void __launch_bounds__(64) hh_gram_kernel(const float* __restrict__ vecs,
                                                     float* __restrict__ G) {
    int i = blockIdx.x >> 4, j = blockIdx.x & 15;
    int lane = threadIdx.x;
    const float4* a = (const float4*)(vecs + i * D);
    const float4* b = (const float4*)(vecs + j * D);
    float s = 0.f;
#pragma unroll
    for (int c = 0; c < CH; ++c) {
        float4 x = a[c * 64 + lane], y = b[c * 64 + lane];
        s += x.x * y.x + x.y * y.y + x.z * y.z + x.w * y.w;
    }
#pragma unroll
    for (int off = 32; off >= 1; off >>= 1) s += __shfl_xor(s, off);
    if (lane == 0) G[i * K + j] = s;
}

// ---------------------------------------------------------------------------
// Kernel 2: build T (upper triangular): H0..H15 = I - V T V^T (larft).
//   T[k][k] = beta_k = 2 / max(G[k][k], EPS)
//   T[i][k] = -beta_k * sum_{j=i}^{k-1} T[i][j] * G[j][k]   (i < k)
// Lower triangle stays 0 (apply kernel sums over all k).
// ---------------------------------------------------------------------------
__global__ void __launch_bounds__(256) hh_buildT_kernel(const float* __restrict__ G,
                                                        float* __restrict__ T) {
    __shared__ float sG[K * K], sT[K * K];
    int t = threadIdx.x;
    sG[t] = G[t]; sT[t] = 0.f;
    __syncthreads();
    for (int k = 0; k < K; ++k) {
        float beta = 2.f / fmaxf(sG[k * K + k], HH_EPS);
        if (t == k) sT[k * K + k] = beta;
        else if (t < k) {
            float s = 0.f;
            for (int j = t; j < k; ++j) s += sT[t * K + j] * sG[j * K + k];
            sT[t * K + k] = -beta * s;
        }
        __syncthreads();
    }
    T[t] = sT[t];
}

// ---------------------------------------------------------------------------
// Apply kernel: compact-WY with V fully LDS-resident.
//
// R8's limit: RR=4 -> ~230 unified regs -> 2 waves/SIMD (can't hide the L2
// v-stream); R9's RR=2 halved regs but DOUBLED L2 v-traffic (each wave
// re-reads all of V). LDS-V breaks the trade-off: v comes from the 69 TB/s
// LDS pipe, the va/vb register buffers disappear, and global traffic is h
// only (131 MB in + 131 MB out). Per-wave register state: h[2][8]=64 +
// temps ~= 95 regs; launch_bounds(1024,4) caps at 128 with real slack
// (R9's spill had slack ~12; tripwire stays WRITE_SIZE == 131072 KB).
// Cross-phase partials in per-wave LDS (the R7 no-spill solution), folded
// 64->8 lanes per phase so everything fits: 128 (V) + 18 (sP) + 4 + 1 =
// 151 KB -> 1 block/CU, 16 waves = 4 waves/SIMD.
// ---------------------------------------------------------------------------
__global__ void __launch_bounds__(1024, 4)
hh_apply_wy(const float* __restrict__ h_in, const float* __restrict__ vecs,
            const float* __restrict__ Tmat, float* __restrict__ h_out) {
    __shared__ float4 sv[K * (D / 4)];          // 128 KB: all 16 vectors
    __shared__ float  sP[WPB * RR * K * SPAD];  // 18 KB: per-wave partials
    __shared__ float  sD[WPB * RR * K];         // 2 KB: reduced dots
    __shared__ float  sW[WPB * RR * K];         // 2 KB: w = P.T
    __shared__ float  sT[K * K];                // 1 KB

    const int t    = threadIdx.x;
    const int wv   = t >> 6;
    const int lane = t & 63;
    const int gw   = blockIdx.x * WPB + wv;
    const size_t rbase = (size_t)gw * RR;

    // h rows into registers (issued first; latency hides under V staging).
    float4 h[RR][CH];
    const float4* hin4 = (const float4*)h_in;
#pragma unroll
    for (int r = 0; r < RR; ++r)
#pragma unroll
        for (int j = 0; j < CH; ++j)
            h[r][j] = hin4[(rbase + r) * (D / 4) + j * 64 + lane];

    // Stage all of V: linear LDS dest + contiguous global source (rule #21).
    const float4* v4 = (const float4*)vecs;
#pragma unroll
    for (int i = 0; i < K * (D / 4) / TPB; ++i) {   // 8 rounds of 16 KB
        int idx = t + i * TPB;
        __builtin_amdgcn_global_load_lds(
            (const __attribute__((address_space(1))) unsigned int*)(v4 + idx),
            (__attribute__((address_space(3))) unsigned int*)(sv + idx),
            16, 0, 0);
    }
    if (t < K * K) sT[t] = Tmat[t];
    __syncthreads();   // only barrier in the kernel

    float* myP = sP + wv * (RR * K * SPAD);
    float* myD = sD + wv * (RR * K);
    float* myW = sW + wv * (RR * K);

    // ---- dot pass: phase k reads v_k from LDS, folds 64->8 lanes -------
#pragma unroll 1
    for (int k = 0; k < K; ++k) {
        float a0x = 0.f, a0y = 0.f, a0z = 0.f, a0w = 0.f;
        float a1x = 0.f, a1y = 0.f, a1z = 0.f, a1w = 0.f;
#pragma unroll
        for (int j = 0; j < CH; ++j) {
            float4 v = sv[k * (D / 4) + j * 64 + lane];
            a0x += h[0][j].x * v.x; a0y += h[0][j].y * v.y;
            a0z += h[0][j].z * v.z; a0w += h[0][j].w * v.w;
            a1x += h[1][j].x * v.x; a1y += h[1][j].y * v.y;
            a1z += h[1][j].z * v.z; a1w += h[1][j].w * v.w;
        }
        float s0 = (a0x + a0y) + (a0z + a0w);
        float s1 = (a1x + a1y) + (a1z + a1w);
        s0 += __shfl_xor(s0, 32); s0 += __shfl_xor(s0, 16); s0 += __shfl_xor(s0, 8);
        s1 += __shfl_xor(s1, 32); s1 += __shfl_xor(s1, 16); s1 += __shfl_xor(s1, 8);
        if (lane < 8) {
            myP[(0 * K + k) * SPAD + lane] = s0;
            myP[(1 * K + k) * SPAD + lane] = s1;
        }
    }

    // ---- final reduce: lane l -> k=l&15, segment l>>4 reads 2 of 8 -----
    const int kk  = lane & 15;
    const int seg = lane >> 4;
#pragma unroll
    for (int r = 0; r < RR; ++r) {
        float s = myP[(r * K + kk) * SPAD + seg * 2]
                + myP[(r * K + kk) * SPAD + seg * 2 + 1];
        s += __shfl_xor(s, 16);
        s += __shfl_xor(s, 32);
        if (lane < 16) myD[r * K + kk] = s;
    }

    // ---- w[j] = sum_k P[k] * T[k][j] (lower triangle of T is 0) --------
#pragma unroll
    for (int r = 0; r < RR; ++r) {
        float wsum = 0.f;
#pragma unroll
        for (int k2 = 0; k2 < K; ++k2)
            wsum += myD[r * K + k2] * sT[k2 * K + kk];   // myD uniform-bcast
        if (lane < 16) myW[r * K + kk] = wsum;
    }

    // ---- update pass: h -= sum_k w_k v_k, v from LDS -------------------
#pragma unroll 1
    for (int k = 0; k < K; ++k) {
        const float w0 = myW[0 * K + k];   // uniform address -> LDS broadcast
        const float w1 = myW[1 * K + k];
#pragma unroll
        for (int j = 0; j < CH; ++j) {
            float4 v = sv[k * (D / 4) + j * 64 + lane];
            h[0][j].x -= w0 * v.x; h[0][j].y -= w0 * v.y;
            h[0][j].z -= w0 * v.z; h[0][j].w -= w0 * v.w;
            h[1][j].x -= w1 * v.x; h[1][j].y -= w1 * v.y;
            h[1][j].z -= w1 * v.z; h[1][j].w -= w1 * v.w;
        }
    }

    // ---- store (h untouched in global between load and here) -----------
#pragma unroll
    for (int r = 0; r < RR; ++r) {
        float4* row = (float4*)h_out + (rbase + r) * (D / 4);
#pragma unroll
        for (int j = 0; j < CH; ++j)
            row[j * 64 + lane] = h[r][j];
    }
}

extern "C" void kernel_launch(void* const* d_in, const int* in_sizes, int n_in,
                              void* d_out, int out_size, void* d_ws, size_t ws_size,
                              hipStream_t stream) {
    const float* h    = (const float*)d_in[0];   // [4,4096,2048] fp32
    const float* vecs = (const float*)d_in[1];   // [16,2048] fp32
    float* out        = (float*)d_out;           // [4,4096,2048] fp32

    float* G  = (float*)d_ws;                    // 256 floats
    float* Tm = G + K * K;                       // 256 floats

    hh_gram_kernel<<<K * K, 64, 0, stream>>>(vecs, G);
    hh_buildT_kernel<<<1, 256, 0, stream>>>(G, Tm);

    int blocks = NROWS / (RR * WPB);             // 512 blocks of 16 waves
    hh_apply_wy<<<blocks, TPB, 0, stream>>>(h, vecs, Tm, out);
}